// Round 17
// baseline (175.280 us; speedup 1.0000x reference)
//
#include <hip/hip_runtime.h>
#include <math.h>

#define N_NODES 50000
#define N_EDGES 800000
#define EP      (N_EDGES + N_NODES)   // edges incl. self loops
#define IN_CH   128
#define HIDC    32
#define HEADS   4
#define OUTC    10
#define NGRAPH  64
#define NEG_SLOPE 0.2f
#define NPAD    50176                  // 128-row padded node count
#define NPART   4
#define PRNG    (N_NODES / NPART)      // 12500 nodes per partition
#define LOG2E   1.44269504088896f
#define SLOT    64                     // per-node edge capacity (P(deg+1>64) ~ 5e-16)

#define GEMM_BLKS (NPAD / 128)                       // 392
#define SCAT_BLKS (((EP + 2047) / 2048) * NPART)     // 1664

typedef unsigned int uint;
typedef __attribute__((ext_vector_type(8))) short bf16x8;
typedef __attribute__((ext_vector_type(4))) float f32x4;

__device__ __forceinline__ float eluf(float x)  { return x > 0.f ? x : __expf(x) - 1.f; }
__device__ __forceinline__ float exp2fast(float x) {   // 2^x, single v_exp_f32
    float r; asm("v_exp_f32 %0, %1" : "=v"(r) : "v"(x)); return r;
}

__device__ __forceinline__ uint bfr(float f) {                 // f32 -> bf16 bits (RNE)
    uint a = __float_as_uint(f);
    return (a + 0x7FFFu + ((a >> 16) & 1u)) >> 16;
}
__device__ __forceinline__ uint bfpair(float lo, float hi) { return bfr(lo) | (bfr(hi) << 16); }
__device__ __forceinline__ float bflo(uint d) { return __uint_as_float(d << 16); }
__device__ __forceinline__ float bfhi(uint d) { return __uint_as_float(d & 0xFFFF0000u); }

// ============ fused: slot-scatter (first) || GEMM1 (2-pass N-split) || w2v ============
// blocks [0, SCAT_BLKS): scatter chunk (int4 scan, NPART=4).
// [SCAT_BLKS, +GEMM_BLKS): gemm1 tile. last block: w2v.
__global__ __launch_bounds__(256) void k_g1scat(const float* __restrict__ x,
                                                const float* __restrict__ W,
                                                const float* __restrict__ a1s, const float* __restrict__ a1d,
                                                uint* __restrict__ h1b,
                                                float4* __restrict__ als1p4, float4* __restrict__ ald1p4,
                                                const int* __restrict__ src, const int* __restrict__ dst,
                                                int* __restrict__ pos, int* __restrict__ esrc,
                                                const float* __restrict__ W2,
                                                const float* __restrict__ a2s, const float* __restrict__ a2d,
                                                float* __restrict__ w2v) {
    __shared__ uint4 WH[1024];          // 16 KB (gemm role only)
    __shared__ uint4 WL[1024];          // 16 KB
    int t = threadIdx.x;
    if (blockIdx.x < SCAT_BLKS) {
        // ---- scatter chunk ----
        int b = blockIdx.x;
        int part = b & (NPART - 1);
        int base = (b >> 2) * 2048;
        int lo = part * PRNG;
        int e0 = base + t * 8;
        if (e0 >= EP) return;
        if (e0 + 8 <= N_EDGES) {
            int4 d0 = *(const int4*)&dst[e0];
            int4 d1 = *(const int4*)&dst[e0 + 4];
            int dd[8] = {d0.x, d0.y, d0.z, d0.w, d1.x, d1.y, d1.z, d1.w};
#pragma unroll
            for (int j = 0; j < 8; ++j) {
                int d = dd[j];
                if ((uint)(d - lo) < PRNG) {
                    int s = src[e0 + j];
                    int p = atomicAdd(&pos[d], 1);
                    if (p < SLOT) esrc[(d << 6) + p] = s;
                }
            }
        } else {
#pragma unroll
            for (int j = 0; j < 8; ++j) {
                int e = e0 + j;
                if (e < EP) {
                    int d, s;
                    if (e < N_EDGES) { d = dst[e]; s = src[e]; }
                    else             { d = e - N_EDGES; s = d; }
                    if ((uint)(d - lo) < PRNG) {
                        int p = atomicAdd(&pos[d], 1);
                        if (p < SLOT) esrc[(d << 6) + p] = s;
                    }
                }
            }
        }
        return;
    }
    if (blockIdx.x == SCAT_BLKS + GEMM_BLKS) {   // ---- w2v ----
        int i = t >> 1, j = t & 1;
        const float* vec = j ? a2d : a2s;
        float s = 0.f;
#pragma unroll
        for (int c = 0; c < 32; ++c)
            s += W2[i * 32 + c] * vec[c];
        w2v[i * 2 + j] = s * LOG2E;
        return;
    }
    // ---- gemm1 role (2-pass N-split) ----
    int gblk = blockIdx.x - SCAT_BLKS;
    uint* whw = (uint*)WH;
    uint* wlw = (uint*)WL;
    int l = t & 63, wid = t >> 6;
    int lr = l & 15, lg = l >> 4;
    int rowb = gblk * 128 + wid * 32;
    int r0 = rowb + lr, r1 = rowb + 16 + lr;
    bool v0r = r0 < N_NODES, v1r = r1 < N_NODES;
    uint4 afr[2][4];
#pragma unroll
    for (int ks = 0; ks < 4; ++ks) {
        int co = (ks * 4 + lg) * 8;
        float4 xa = {0,0,0,0}, xb_ = {0,0,0,0}, xc = {0,0,0,0}, xd = {0,0,0,0};
        if (v0r) { xa = *(const float4*)&x[r0 * 128 + co]; xb_ = *(const float4*)&x[r0 * 128 + co + 4]; }
        if (v1r) { xc = *(const float4*)&x[r1 * 128 + co]; xd = *(const float4*)&x[r1 * 128 + co + 4]; }
        afr[0][ks] = make_uint4(bfpair(xa.x, xa.y), bfpair(xa.z, xa.w), bfpair(xb_.x, xb_.y), bfpair(xb_.z, xb_.w));
        afr[1][ks] = make_uint4(bfpair(xc.x, xc.y), bfpair(xc.z, xc.w), bfpair(xd.x, xd.y), bfpair(xd.z, xd.w));
    }
    float as_[8], ad_[8];
#pragma unroll
    for (int nt = 0; nt < 8; ++nt) {
        as_[nt] = a1s[nt * 16 + lr] * LOG2E;
        ad_[nt] = a1d[nt * 16 + lr] * LOG2E;
    }
    f32x4 acc[2][8] = {};
    for (int pass = 0; pass < 2; ++pass) {
        int colbase = pass * 64;
        __syncthreads();
        for (int it = 0; it < 8; ++it) {
            int u = it * 256 + t;
            int n = u & 63, kq = u >> 6;
            float w0 = W[(kq * 4 + 0) * 128 + colbase + n];
            float w1 = W[(kq * 4 + 1) * 128 + colbase + n];
            float w2 = W[(kq * 4 + 2) * 128 + colbase + n];
            float w3 = W[(kq * 4 + 3) * 128 + colbase + n];
            uint h0 = bfr(w0), h1 = bfr(w1), h2 = bfr(w2), h3 = bfr(w3);
            float l0 = w0 - __uint_as_float(h0 << 16);
            float l1 = w1 - __uint_as_float(h1 << 16);
            float l2 = w2 - __uint_as_float(h2 << 16);
            float l3 = w3 - __uint_as_float(h3 << 16);
            int word = n * 64 + (((kq >> 1) ^ (n & 7)) << 2) + (kq & 1) * 2;
            *(uint2*)&whw[word] = make_uint2(h0 | (h1 << 16), h2 | (h3 << 16));
            *(uint2*)&wlw[word] = make_uint2(bfr(l0) | (bfr(l1) << 16), bfr(l2) | (bfr(l3) << 16));
        }
        __syncthreads();
#pragma unroll
        for (int ks = 0; ks < 4; ++ks) {
            bf16x8 a0 = *reinterpret_cast<bf16x8*>(&afr[0][ks]);
            bf16x8 a1 = *reinterpret_cast<bf16x8*>(&afr[1][ks]);
            int quw = ks * 4 + lg;
#pragma unroll
            for (int nt = 0; nt < 4; ++nt) {
                int n = nt * 16 + lr;
                int idx = n * 16 + (quw ^ (n & 7));
                bf16x8 bh = *reinterpret_cast<bf16x8*>(&WH[idx]);
                bf16x8 bl = *reinterpret_cast<bf16x8*>(&WL[idx]);
                int g = pass * 4 + nt;
                acc[0][g] = __builtin_amdgcn_mfma_f32_16x16x32_bf16(a0, bh, acc[0][g], 0, 0, 0);
                acc[0][g] = __builtin_amdgcn_mfma_f32_16x16x32_bf16(a0, bl, acc[0][g], 0, 0, 0);
                acc[1][g] = __builtin_amdgcn_mfma_f32_16x16x32_bf16(a1, bh, acc[1][g], 0, 0, 0);
                acc[1][g] = __builtin_amdgcn_mfma_f32_16x16x32_bf16(a1, bl, acc[1][g], 0, 0, 0);
            }
        }
    }
    // epilogue: h1b pack + attention logits from f32 acc
#pragma unroll
    for (int mt = 0; mt < 2; ++mt)
#pragma unroll
        for (int r = 0; r < 4; ++r) {
            int row = rowb + mt * 16 + 4 * lg + r;
            float ps0 = acc[mt][0][r] * as_[0] + acc[mt][1][r] * as_[1];
            float ps1 = acc[mt][2][r] * as_[2] + acc[mt][3][r] * as_[3];
            float ps2 = acc[mt][4][r] * as_[4] + acc[mt][5][r] * as_[5];
            float ps3 = acc[mt][6][r] * as_[6] + acc[mt][7][r] * as_[7];
            float pd0 = acc[mt][0][r] * ad_[0] + acc[mt][1][r] * ad_[1];
            float pd1 = acc[mt][2][r] * ad_[2] + acc[mt][3][r] * ad_[3];
            float pd2 = acc[mt][4][r] * ad_[4] + acc[mt][5][r] * ad_[5];
            float pd3 = acc[mt][6][r] * ad_[6] + acc[mt][7][r] * ad_[7];
#pragma unroll
            for (int off = 1; off < 16; off <<= 1) {
                ps0 += __shfl_xor(ps0, off); ps1 += __shfl_xor(ps1, off);
                ps2 += __shfl_xor(ps2, off); ps3 += __shfl_xor(ps3, off);
                pd0 += __shfl_xor(pd0, off); pd1 += __shfl_xor(pd1, off);
                pd2 += __shfl_xor(pd2, off); pd3 += __shfl_xor(pd3, off);
            }
            if (row < N_NODES) {
                if (lr == 0) {
                    float4 sv = {ps0, ps2, ps1, ps3};   // {s0,s2,s1,s3} pairs (hh0, hh0+2)
                    float4 dv = {pd0, pd2, pd1, pd3};
                    als1p4[row] = sv;
                    ald1p4[row] = dv;
                }
#pragma unroll
                for (int nt = 0; nt < 4; ++nt)
                    h1b[row * 64 + nt * 16 + lr] = bfpair(acc[mt][nt][r], acc[mt][nt + 4][r]);
            }
        }
}

// ---------------- agg1: single pass, quarter-wave per edge, slot-based ----------------
__global__ __launch_bounds__(256) void k_agg1(const uint4* __restrict__ h1b4,
                                              const int* __restrict__ pos, const int* __restrict__ esrc,
                                              const float2* __restrict__ als1p, const float2* __restrict__ ald1p,
                                              const float* __restrict__ b1,
                                              const float* __restrict__ w2v,
                                              uint2* __restrict__ o1b2,
                                              float* __restrict__ als2, float* __restrict__ ald2) {
    int l = threadIdx.x & 63;
    int wv = threadIdx.x >> 6;
    int n = blockIdx.x * 4 + wv;
    int s = n << 6;
    int e = s + min(pos[n], SLOT);
    int sub = l >> 4, cp4 = l & 15, hh0 = cp4 >> 3;   // heads (hh0, hh0+2)
    float2 ad = ald1p[n * 2 + hh0];
    float aL0=0,aL1=0,aL2=0,aL3=0,aH0=0,aH1=0,aH2=0,aH3=0, ss0=0, ss1=0;
#pragma unroll 4
    for (int i = s + sub; i < e; i += 4) {
        int sa = esrc[i];
        float2 av = als1p[sa * 2 + hh0];
        float z0 = av.x + ad.x, z1 = av.y + ad.y;
        float e0 = exp2fast(fmaxf(z0, NEG_SLOPE * z0));
        float e1 = exp2fast(fmaxf(z1, NEG_SLOPE * z1));
        uint4 d = h1b4[sa * 16 + cp4];
        ss0 += e0; ss1 += e1;
        aL0 += e0 * bflo(d.x); aH0 += e1 * bfhi(d.x);
        aL1 += e0 * bflo(d.y); aH1 += e1 * bfhi(d.y);
        aL2 += e0 * bflo(d.z); aH2 += e1 * bfhi(d.z);
        aL3 += e0 * bflo(d.w); aH3 += e1 * bfhi(d.w);
    }
    // reduce across subs (lane bits 4,5)
    ss0 += __shfl_xor(ss0, 16); ss0 += __shfl_xor(ss0, 32);
    ss1 += __shfl_xor(ss1, 16); ss1 += __shfl_xor(ss1, 32);
    aL0 += __shfl_xor(aL0, 16); aL0 += __shfl_xor(aL0, 32);
    aL1 += __shfl_xor(aL1, 16); aL1 += __shfl_xor(aL1, 32);
    aL2 += __shfl_xor(aL2, 16); aL2 += __shfl_xor(aL2, 32);
    aL3 += __shfl_xor(aL3, 16); aL3 += __shfl_xor(aL3, 32);
    aH0 += __shfl_xor(aH0, 16); aH0 += __shfl_xor(aH0, 32);
    aH1 += __shfl_xor(aH1, 16); aH1 += __shfl_xor(aH1, 32);
    aH2 += __shfl_xor(aH2, 16); aH2 += __shfl_xor(aH2, 32);
    aH3 += __shfl_xor(aH3, 16); aH3 += __shfl_xor(aH3, 32);
    if (sub == 0) {
        float inv0 = 1.f / ss0, inv1 = 1.f / ss1;
        float4 bbL = *(const float4*)&b1[cp4 * 4];
        float4 bbH = *(const float4*)&b1[64 + cp4 * 4];
        float v0 = eluf(aL0 * inv0 + bbL.x);
        float v1 = eluf(aL1 * inv0 + bbL.y);
        float v2 = eluf(aL2 * inv0 + bbL.z);
        float v3 = eluf(aL3 * inv0 + bbL.w);
        float u0 = eluf(aH0 * inv1 + bbH.x);
        float u1 = eluf(aH1 * inv1 + bbH.y);
        float u2 = eluf(aH2 * inv1 + bbH.z);
        float u3 = eluf(aH3 * inv1 + bbH.w);
        o1b2[n * 32 + cp4]      = make_uint2(bfpair(v0, v1), bfpair(v2, v3));
        o1b2[n * 32 + 16 + cp4] = make_uint2(bfpair(u0, u1), bfpair(u2, u3));
        // conv2 logits: channels 4cp4..4cp4+3 and 64+4cp4..64+4cp4+3
        const float4* w2 = (const float4*)w2v;
        float4 wa = w2[2 * cp4], wb = w2[2 * cp4 + 1];
        float4 wc = w2[32 + 2 * cp4], wd = w2[32 + 2 * cp4 + 1];
        float p0 = v0*wa.x + v1*wa.z + v2*wb.x + v3*wb.z + u0*wc.x + u1*wc.z + u2*wd.x + u3*wd.z;
        float p1 = v0*wa.y + v1*wa.w + v2*wb.y + v3*wb.w + u0*wc.y + u1*wc.w + u2*wd.y + u3*wd.w;
        p0 += __shfl_xor(p0, 1); p0 += __shfl_xor(p0, 2);
        p0 += __shfl_xor(p0, 4); p0 += __shfl_xor(p0, 8);
        p1 += __shfl_xor(p1, 1); p1 += __shfl_xor(p1, 2);
        p1 += __shfl_xor(p1, 4); p1 += __shfl_xor(p1, 8);
        if (cp4 == 0) { als2[n] = p0; ald2[n] = p1; }
    }
}

// ---------------- GEMM2 (MFMA): h2b = bf16( o1b @ (W2hi+W2lo) ), dword w = chs (w, w+16) ----------------
__global__ __launch_bounds__(256) void k_gemm2(const uint4* __restrict__ ob4,
                                               const float* __restrict__ W,
                                               uint* __restrict__ h2b) {
    __shared__ uint4 WH[512];           // Wt_hi[n 0..31][k] swizzled, 8 KB
    __shared__ uint4 WL[512];
    int t = threadIdx.x;
    uint* whw = (uint*)WH;
    uint* wlw = (uint*)WL;
    for (int it = 0; it < 4; ++it) {
        int u = it * 256 + t;
        int n = u & 31, kq = u >> 5;
        float w0 = W[(kq * 4 + 0) * 32 + n];
        float w1 = W[(kq * 4 + 1) * 32 + n];
        float w2 = W[(kq * 4 + 2) * 32 + n];
        float w3 = W[(kq * 4 + 3) * 32 + n];
        uint h0 = bfr(w0), h1 = bfr(w1), h2 = bfr(w2), h3 = bfr(w3);
        float l0 = w0 - __uint_as_float(h0 << 16);
        float l1 = w1 - __uint_as_float(h1 << 16);
        float l2 = w2 - __uint_as_float(h2 << 16);
        float l3 = w3 - __uint_as_float(h3 << 16);
        int word = n * 64 + (((kq >> 1) ^ (n & 7)) << 2) + (kq & 1) * 2;
        *(uint2*)&whw[word] = make_uint2(h0 | (h1 << 16), h2 | (h3 << 16));
        *(uint2*)&wlw[word] = make_uint2(bfr(l0) | (bfr(l1) << 16), bfr(l2) | (bfr(l3) << 16));
    }
    __syncthreads();
    int l = t & 63, wid = t >> 6;
    int lr = l & 15, lg = l >> 4;
    int rowb = blockIdx.x * 128 + wid * 32;
    f32x4 acc[2][2] = {};
#pragma unroll
    for (int ks = 0; ks < 4; ++ks) {
        uint4 av0 = ob4[(rowb + lr) * 16 + ks * 4 + lg];
        uint4 av1 = ob4[(rowb + 16 + lr) * 16 + ks * 4 + lg];
        bf16x8 a0 = *reinterpret_cast<bf16x8*>(&av0);
        bf16x8 a1 = *reinterpret_cast<bf16x8*>(&av1);
        int quw = ks * 4 + lg;
#pragma unroll
        for (int nt = 0; nt < 2; ++nt) {
            int n = nt * 16 + lr;
            int idx = n * 16 + (quw ^ (n & 7));
            bf16x8 bh = *reinterpret_cast<bf16x8*>(&WH[idx]);
            bf16x8 bl = *reinterpret_cast<bf16x8*>(&WL[idx]);
            acc[0][nt] = __builtin_amdgcn_mfma_f32_16x16x32_bf16(a0, bh, acc[0][nt], 0, 0, 0);
            acc[0][nt] = __builtin_amdgcn_mfma_f32_16x16x32_bf16(a0, bl, acc[0][nt], 0, 0, 0);
            acc[1][nt] = __builtin_amdgcn_mfma_f32_16x16x32_bf16(a1, bh, acc[1][nt], 0, 0, 0);
            acc[1][nt] = __builtin_amdgcn_mfma_f32_16x16x32_bf16(a1, bl, acc[1][nt], 0, 0, 0);
        }
    }
#pragma unroll
    for (int mt = 0; mt < 2; ++mt)
#pragma unroll
        for (int r = 0; r < 4; ++r) {
            int row = rowb + mt * 16 + 4 * lg + r;
            if (row < N_NODES)
                h2b[row * 16 + lr] = bfpair(acc[mt][0][r], acc[mt][1][r]);
        }
}

// ---------------- agg2: single pass, eighth-wave per edge, slot-based ----------------
__global__ __launch_bounds__(256) void k_agg2(const uint2* __restrict__ h2b2,
                                              const int* __restrict__ pos, const int* __restrict__ esrc,
                                              const float* __restrict__ als, const float* __restrict__ ald,
                                              const float* __restrict__ b2,
                                              float* __restrict__ o2) {
    int l = threadIdx.x & 63;
    int wv = threadIdx.x >> 6;
    int n = blockIdx.x * 4 + wv;
    int s = n << 6;
    int e = s + min(pos[n], SLOT);
    int sub = l >> 3, cp8 = l & 7;       // dwords 2cp8, 2cp8+1 -> chs {2cp8(+1), 2cp8(+1)+16}
    float ad = ald[n];
    float a0 = 0, a1 = 0, a2 = 0, a3 = 0, ss = 0;
#pragma unroll 4
    for (int i = s + sub; i < e; i += 8) {
        int sa = esrc[i];
        float z = als[sa] + ad;
        float wgt = exp2fast(fmaxf(z, NEG_SLOPE * z));
        uint2 d = h2b2[sa * 8 + cp8];
        ss += wgt;
        a0 += wgt * bflo(d.x); a1 += wgt * bfhi(d.x);
        a2 += wgt * bflo(d.y); a3 += wgt * bfhi(d.y);
    }
    ss += __shfl_xor(ss, 8); ss += __shfl_xor(ss, 16); ss += __shfl_xor(ss, 32);
    a0 += __shfl_xor(a0, 8); a0 += __shfl_xor(a0, 16); a0 += __shfl_xor(a0, 32);
    a1 += __shfl_xor(a1, 8); a1 += __shfl_xor(a1, 16); a1 += __shfl_xor(a1, 32);
    a2 += __shfl_xor(a2, 8); a2 += __shfl_xor(a2, 16); a2 += __shfl_xor(a2, 32);
    a3 += __shfl_xor(a3, 8); a3 += __shfl_xor(a3, 16); a3 += __shfl_xor(a3, 32);
    if (sub == 0) {
        float inv = 1.f / ss;
        int c = 2 * cp8;
        float2 lo = { eluf(a0 * inv + b2[c]),      eluf(a2 * inv + b2[c + 1]) };
        float2 hi = { eluf(a1 * inv + b2[c + 16]), eluf(a3 * inv + b2[c + 17]) };
        *(float2*)&o2[n * 32 + c]      = lo;
        *(float2*)&o2[n * 32 + 16 + c] = hi;
    }
}

// ---------------- fused pool + final linear (inline boundary search) ----------------
__global__ __launch_bounds__(256) void k_poolfinal(const float* __restrict__ out2,
                                                   const int* __restrict__ batch,
                                                   const float* __restrict__ Wl,
                                                   const float* __restrict__ bl,
                                                   float* __restrict__ out) {
    __shared__ float red[4][32];
    __shared__ float pooled[32];
    int g = blockIdx.x;
    int s = 0, hi = N_NODES;
    while (s < hi) { int mid = (s + hi) >> 1; if (batch[mid] < g) s = mid + 1; else hi = mid; }
    int e = s; hi = N_NODES;
    while (e < hi) { int mid = (e + hi) >> 1; if (batch[mid] < g + 1) e = mid + 1; else hi = mid; }
    int t = threadIdx.x;
    int c = t & 31, r = t >> 5;
    float acc = 0.f;
    for (int i = s + r; i < e; i += 8)
        acc += out2[i * 32 + c];
    acc += __shfl_xor(acc, 32);
    if ((t & 63) < 32) red[t >> 6][c] = acc;
    __syncthreads();
    if (t < 32) {
        float v = red[0][t] + red[1][t] + red[2][t] + red[3][t];
        float cnt = fmaxf((float)(e - s), 1.f);
        pooled[t] = v / cnt;
    }
    __syncthreads();
    if (t < OUTC) {
        float a = 0.f;
        for (int cc = 0; cc < HIDC; cc++)
            a += pooled[cc] * Wl[cc * OUTC + t];
        out[g * OUTC + t] = a + bl[t];
    }
}

extern "C" void kernel_launch(void* const* d_in, const int* in_sizes, int n_in,
                              void* d_out, int out_size, void* d_ws, size_t ws_size,
                              hipStream_t stream) {
    (void)in_sizes; (void)n_in; (void)out_size; (void)ws_size;
    const float* x    = (const float*)d_in[0];
    const int*   ei   = (const int*)d_in[1];
    const int*   srcA = ei;
    const int*   dstA = ei + N_EDGES;
    const int*   batch = (const int*)d_in[2];
    const float* W1  = (const float*)d_in[3];
    const float* a1s = (const float*)d_in[4];
    const float* a1d = (const float*)d_in[5];
    const float* b1  = (const float*)d_in[6];
    const float* W2  = (const float*)d_in[7];
    const float* a2s = (const float*)d_in[8];
    const float* a2d = (const float*)d_in[9];
    const float* b2  = (const float*)d_in[10];
    const float* Wl  = (const float*)d_in[11];
    const float* bl  = (const float*)d_in[12];
    float* out = (float*)d_out;

    char* w = (char*)d_ws;
    auto alloc = [&](size_t bytes) -> void* {
        void* p = (void*)w;
        w += (bytes + 255) & ~(size_t)255;
        return p;
    };
    uint*  h1b  = (uint*)alloc((size_t)N_NODES * 64 * 4);    // 12.8 MB
    uint*  o1b  = (uint*)alloc((size_t)NPAD * 64 * 4);       // 12.85 MB
    uint*  h2b  = (uint*)alloc((size_t)N_NODES * 16 * 4);    // 3.2 MB
    float* o2   = (float*)alloc((size_t)N_NODES * 32 * 4);   // 6.4 MB
    float* als1 = (float*)alloc((size_t)N_NODES * 4 * 4);
    float* ald1 = (float*)alloc((size_t)N_NODES * 4 * 4);
    float* als2 = (float*)alloc((size_t)N_NODES * 4);
    float* ald2 = (float*)alloc((size_t)N_NODES * 4);
    float* w2v  = (float*)alloc(256 * 4);
    int*   pos  = (int*)alloc((size_t)N_NODES * 4);
    int*   esrc = (int*)alloc((size_t)N_NODES * SLOT * 4);   // 12.8 MB slots

    hipMemsetAsync(pos, 0, (size_t)N_NODES * 4, stream);
    k_g1scat<<<SCAT_BLKS + GEMM_BLKS + 1, 256, 0, stream>>>(x, W1, a1s, a1d,
                                                            h1b, (float4*)als1, (float4*)ald1,
                                                            srcA, dstA, pos, esrc,
                                                            W2, a2s, a2d, w2v);
    k_agg1<<<N_NODES / 4, 256, 0, stream>>>((const uint4*)h1b, pos, esrc,
                                            (const float2*)als1, (const float2*)ald1, b1, w2v,
                                            (uint2*)o1b, als2, ald2);
    k_gemm2<<<NPAD / 128, 256, 0, stream>>>((const uint4*)o1b, W2, h2b);
    k_agg2<<<N_NODES / 4, 256, 0, stream>>>((const uint2*)h2b, pos, esrc, als2, ald2, b2, o2);
    k_poolfinal<<<NGRAPH, 256, 0, stream>>>(o2, batch, Wl, bl, out);
}

// Round 18
// 164.828 us; speedup vs baseline: 1.0634x; 1.0634x over previous
//
#include <hip/hip_runtime.h>
#include <math.h>

#define N_NODES 50000
#define N_EDGES 800000
#define EP      (N_EDGES + N_NODES)   // edges incl. self loops
#define IN_CH   128
#define HIDC    32
#define HEADS   4
#define OUTC    10
#define NGRAPH  64
#define NEG_SLOPE 0.2f
#define NPAD    50176                  // 128-row padded node count
#define NPART   8
#define PRNG    (N_NODES / NPART)      // 6250 nodes per partition
#define LOG2E   1.44269504088896f
#define SLOT    64                     // per-node edge capacity (P(deg+1>64) ~ 5e-16)

#define GEMM_BLKS (NPAD / 128)                       // 392
#define SCAT_BLKS (((EP + 2047) / 2048) * NPART)     // 3328

typedef unsigned int uint;
typedef __attribute__((ext_vector_type(8))) short bf16x8;
typedef __attribute__((ext_vector_type(4))) float f32x4;

__device__ __forceinline__ float eluf(float x)  { return x > 0.f ? x : __expf(x) - 1.f; }
__device__ __forceinline__ float exp2fast(float x) {   // 2^x, single v_exp_f32
    float r; asm("v_exp_f32 %0, %1" : "=v"(r) : "v"(x)); return r;
}

__device__ __forceinline__ uint bfr(float f) {                 // f32 -> bf16 bits (RNE)
    uint a = __float_as_uint(f);
    return (a + 0x7FFFu + ((a >> 16) & 1u)) >> 16;
}
__device__ __forceinline__ uint bfpair(float lo, float hi) { return bfr(lo) | (bfr(hi) << 16); }
__device__ __forceinline__ float bflo(uint d) { return __uint_as_float(d << 16); }
__device__ __forceinline__ float bfhi(uint d) { return __uint_as_float(d & 0xFFFF0000u); }

// ============ fused: GEMM1 (2-pass N-split, 32KB LDS) || slot-scatter || w2v ============
// blocks [0, GEMM_BLKS): gemm1 tile.  [GEMM_BLKS, +SCAT_BLKS): scatter chunk
// (int4 scan of BOTH dst and src -> no dependent load on the atomic chain).
__global__ __launch_bounds__(256) void k_g1scat(const float* __restrict__ x,
                                                const float* __restrict__ W,
                                                const float* __restrict__ a1s, const float* __restrict__ a1d,
                                                uint* __restrict__ h1b,
                                                float4* __restrict__ als1p4, float4* __restrict__ ald1p4,
                                                const int* __restrict__ src, const int* __restrict__ dst,
                                                int* __restrict__ pos, int* __restrict__ esrc,
                                                const float* __restrict__ W2,
                                                const float* __restrict__ a2s, const float* __restrict__ a2d,
                                                float* __restrict__ w2v) {
    __shared__ uint4 WH[1024];          // 16 KB (gemm role only)
    __shared__ uint4 WL[1024];          // 16 KB
    int t = threadIdx.x;
    if (blockIdx.x >= GEMM_BLKS) {
        int b = blockIdx.x - GEMM_BLKS;
        if (b == SCAT_BLKS) {           // ---- w2v ----
            int i = t >> 1, j = t & 1;
            const float* vec = j ? a2d : a2s;
            float s = 0.f;
#pragma unroll
            for (int c = 0; c < 32; ++c)
                s += W2[i * 32 + c] * vec[c];
            w2v[i * 2 + j] = s * LOG2E;
            return;
        }
        // ---- scatter chunk ----
        int part = b & (NPART - 1);
        int base = (b >> 3) * 2048;
        int lo = part * PRNG;
        int e0 = base + t * 8;
        if (e0 >= EP) return;
        if (e0 + 8 <= N_EDGES) {
            int4 d0 = *(const int4*)&dst[e0];
            int4 d1 = *(const int4*)&dst[e0 + 4];
            int4 s0 = *(const int4*)&src[e0];
            int4 s1 = *(const int4*)&src[e0 + 4];
            int dd[8] = {d0.x, d0.y, d0.z, d0.w, d1.x, d1.y, d1.z, d1.w};
            int ssv[8] = {s0.x, s0.y, s0.z, s0.w, s1.x, s1.y, s1.z, s1.w};
#pragma unroll
            for (int j = 0; j < 8; ++j) {
                int d = dd[j];
                if ((uint)(d - lo) < PRNG) {
                    int p = atomicAdd(&pos[d], 1);
                    if (p < SLOT) esrc[(d << 6) + p] = ssv[j];
                }
            }
        } else {
#pragma unroll
            for (int j = 0; j < 8; ++j) {
                int e = e0 + j;
                if (e < EP) {
                    int d, s;
                    if (e < N_EDGES) { d = dst[e]; s = src[e]; }
                    else             { d = e - N_EDGES; s = d; }
                    if ((uint)(d - lo) < PRNG) {
                        int p = atomicAdd(&pos[d], 1);
                        if (p < SLOT) esrc[(d << 6) + p] = s;
                    }
                }
            }
        }
        return;
    }
    // ---- gemm1 role (2-pass N-split) ----
    uint* whw = (uint*)WH;
    uint* wlw = (uint*)WL;
    int l = t & 63, wid = t >> 6;
    int lr = l & 15, lg = l >> 4;
    int rowb = blockIdx.x * 128 + wid * 32;
    int r0 = rowb + lr, r1 = rowb + 16 + lr;
    bool v0r = r0 < N_NODES, v1r = r1 < N_NODES;
    uint4 afr[2][4];
#pragma unroll
    for (int ks = 0; ks < 4; ++ks) {
        int co = (ks * 4 + lg) * 8;
        float4 xa = {0,0,0,0}, xb_ = {0,0,0,0}, xc = {0,0,0,0}, xd = {0,0,0,0};
        if (v0r) { xa = *(const float4*)&x[r0 * 128 + co]; xb_ = *(const float4*)&x[r0 * 128 + co + 4]; }
        if (v1r) { xc = *(const float4*)&x[r1 * 128 + co]; xd = *(const float4*)&x[r1 * 128 + co + 4]; }
        afr[0][ks] = make_uint4(bfpair(xa.x, xa.y), bfpair(xa.z, xa.w), bfpair(xb_.x, xb_.y), bfpair(xb_.z, xb_.w));
        afr[1][ks] = make_uint4(bfpair(xc.x, xc.y), bfpair(xc.z, xc.w), bfpair(xd.x, xd.y), bfpair(xd.z, xd.w));
    }
    float as_[8], ad_[8];
#pragma unroll
    for (int nt = 0; nt < 8; ++nt) {
        as_[nt] = a1s[nt * 16 + lr] * LOG2E;
        ad_[nt] = a1d[nt * 16 + lr] * LOG2E;
    }
    f32x4 acc[2][8] = {};
    for (int pass = 0; pass < 2; ++pass) {
        int colbase = pass * 64;
        __syncthreads();
        for (int it = 0; it < 8; ++it) {
            int u = it * 256 + t;
            int n = u & 63, kq = u >> 6;
            float w0 = W[(kq * 4 + 0) * 128 + colbase + n];
            float w1 = W[(kq * 4 + 1) * 128 + colbase + n];
            float w2 = W[(kq * 4 + 2) * 128 + colbase + n];
            float w3 = W[(kq * 4 + 3) * 128 + colbase + n];
            uint h0 = bfr(w0), h1 = bfr(w1), h2 = bfr(w2), h3 = bfr(w3);
            float l0 = w0 - __uint_as_float(h0 << 16);
            float l1 = w1 - __uint_as_float(h1 << 16);
            float l2 = w2 - __uint_as_float(h2 << 16);
            float l3 = w3 - __uint_as_float(h3 << 16);
            int word = n * 64 + (((kq >> 1) ^ (n & 7)) << 2) + (kq & 1) * 2;
            *(uint2*)&whw[word] = make_uint2(h0 | (h1 << 16), h2 | (h3 << 16));
            *(uint2*)&wlw[word] = make_uint2(bfr(l0) | (bfr(l1) << 16), bfr(l2) | (bfr(l3) << 16));
        }
        __syncthreads();
#pragma unroll
        for (int ks = 0; ks < 4; ++ks) {
            bf16x8 a0 = *reinterpret_cast<bf16x8*>(&afr[0][ks]);
            bf16x8 a1 = *reinterpret_cast<bf16x8*>(&afr[1][ks]);
            int quw = ks * 4 + lg;
#pragma unroll
            for (int nt = 0; nt < 4; ++nt) {
                int n = nt * 16 + lr;
                int idx = n * 16 + (quw ^ (n & 7));
                bf16x8 bh = *reinterpret_cast<bf16x8*>(&WH[idx]);
                bf16x8 bl = *reinterpret_cast<bf16x8*>(&WL[idx]);
                int g = pass * 4 + nt;
                acc[0][g] = __builtin_amdgcn_mfma_f32_16x16x32_bf16(a0, bh, acc[0][g], 0, 0, 0);
                acc[0][g] = __builtin_amdgcn_mfma_f32_16x16x32_bf16(a0, bl, acc[0][g], 0, 0, 0);
                acc[1][g] = __builtin_amdgcn_mfma_f32_16x16x32_bf16(a1, bh, acc[1][g], 0, 0, 0);
                acc[1][g] = __builtin_amdgcn_mfma_f32_16x16x32_bf16(a1, bl, acc[1][g], 0, 0, 0);
            }
        }
    }
    // epilogue: h1b pack + attention logits from f32 acc
#pragma unroll
    for (int mt = 0; mt < 2; ++mt)
#pragma unroll
        for (int r = 0; r < 4; ++r) {
            int row = rowb + mt * 16 + 4 * lg + r;
            float ps0 = acc[mt][0][r] * as_[0] + acc[mt][1][r] * as_[1];
            float ps1 = acc[mt][2][r] * as_[2] + acc[mt][3][r] * as_[3];
            float ps2 = acc[mt][4][r] * as_[4] + acc[mt][5][r] * as_[5];
            float ps3 = acc[mt][6][r] * as_[6] + acc[mt][7][r] * as_[7];
            float pd0 = acc[mt][0][r] * ad_[0] + acc[mt][1][r] * ad_[1];
            float pd1 = acc[mt][2][r] * ad_[2] + acc[mt][3][r] * ad_[3];
            float pd2 = acc[mt][4][r] * ad_[4] + acc[mt][5][r] * ad_[5];
            float pd3 = acc[mt][6][r] * ad_[6] + acc[mt][7][r] * ad_[7];
#pragma unroll
            for (int off = 1; off < 16; off <<= 1) {
                ps0 += __shfl_xor(ps0, off); ps1 += __shfl_xor(ps1, off);
                ps2 += __shfl_xor(ps2, off); ps3 += __shfl_xor(ps3, off);
                pd0 += __shfl_xor(pd0, off); pd1 += __shfl_xor(pd1, off);
                pd2 += __shfl_xor(pd2, off); pd3 += __shfl_xor(pd3, off);
            }
            if (row < N_NODES) {
                if (lr == 0) {
                    float4 sv = {ps0, ps2, ps1, ps3};   // {s0,s2,s1,s3} pairs (hh0, hh0+2)
                    float4 dv = {pd0, pd2, pd1, pd3};
                    als1p4[row] = sv;
                    ald1p4[row] = dv;
                }
#pragma unroll
                for (int nt = 0; nt < 4; ++nt)
                    h1b[row * 64 + nt * 16 + lr] = bfpair(acc[mt][nt][r], acc[mt][nt + 4][r]);
            }
        }
}

// ---------------- agg1: single pass, quarter-wave per edge, slot-based ----------------
__global__ __launch_bounds__(256) void k_agg1(const uint4* __restrict__ h1b4,
                                              const int* __restrict__ pos, const int* __restrict__ esrc,
                                              const float2* __restrict__ als1p, const float2* __restrict__ ald1p,
                                              const float* __restrict__ b1,
                                              const float* __restrict__ w2v,
                                              uint2* __restrict__ o1b2,
                                              float* __restrict__ als2, float* __restrict__ ald2) {
    int l = threadIdx.x & 63;
    int wv = threadIdx.x >> 6;
    int n = blockIdx.x * 4 + wv;
    int s = n << 6;
    int e = s + min(pos[n], SLOT);
    int sub = l >> 4, cp4 = l & 15, hh0 = cp4 >> 3;   // heads (hh0, hh0+2)
    float2 ad = ald1p[n * 2 + hh0];
    float aL0=0,aL1=0,aL2=0,aL3=0,aH0=0,aH1=0,aH2=0,aH3=0, ss0=0, ss1=0;
#pragma unroll 4
    for (int i = s + sub; i < e; i += 4) {
        int sa = esrc[i];
        float2 av = als1p[sa * 2 + hh0];
        float z0 = av.x + ad.x, z1 = av.y + ad.y;
        float e0 = exp2fast(fmaxf(z0, NEG_SLOPE * z0));
        float e1 = exp2fast(fmaxf(z1, NEG_SLOPE * z1));
        uint4 d = h1b4[sa * 16 + cp4];
        ss0 += e0; ss1 += e1;
        aL0 += e0 * bflo(d.x); aH0 += e1 * bfhi(d.x);
        aL1 += e0 * bflo(d.y); aH1 += e1 * bfhi(d.y);
        aL2 += e0 * bflo(d.z); aH2 += e1 * bfhi(d.z);
        aL3 += e0 * bflo(d.w); aH3 += e1 * bfhi(d.w);
    }
    // reduce across subs (lane bits 4,5)
    ss0 += __shfl_xor(ss0, 16); ss0 += __shfl_xor(ss0, 32);
    ss1 += __shfl_xor(ss1, 16); ss1 += __shfl_xor(ss1, 32);
    aL0 += __shfl_xor(aL0, 16); aL0 += __shfl_xor(aL0, 32);
    aL1 += __shfl_xor(aL1, 16); aL1 += __shfl_xor(aL1, 32);
    aL2 += __shfl_xor(aL2, 16); aL2 += __shfl_xor(aL2, 32);
    aL3 += __shfl_xor(aL3, 16); aL3 += __shfl_xor(aL3, 32);
    aH0 += __shfl_xor(aH0, 16); aH0 += __shfl_xor(aH0, 32);
    aH1 += __shfl_xor(aH1, 16); aH1 += __shfl_xor(aH1, 32);
    aH2 += __shfl_xor(aH2, 16); aH2 += __shfl_xor(aH2, 32);
    aH3 += __shfl_xor(aH3, 16); aH3 += __shfl_xor(aH3, 32);
    if (sub == 0) {
        float inv0 = 1.f / ss0, inv1 = 1.f / ss1;
        float4 bbL = *(const float4*)&b1[cp4 * 4];
        float4 bbH = *(const float4*)&b1[64 + cp4 * 4];
        float v0 = eluf(aL0 * inv0 + bbL.x);
        float v1 = eluf(aL1 * inv0 + bbL.y);
        float v2 = eluf(aL2 * inv0 + bbL.z);
        float v3 = eluf(aL3 * inv0 + bbL.w);
        float u0 = eluf(aH0 * inv1 + bbH.x);
        float u1 = eluf(aH1 * inv1 + bbH.y);
        float u2 = eluf(aH2 * inv1 + bbH.z);
        float u3 = eluf(aH3 * inv1 + bbH.w);
        o1b2[n * 32 + cp4]      = make_uint2(bfpair(v0, v1), bfpair(v2, v3));
        o1b2[n * 32 + 16 + cp4] = make_uint2(bfpair(u0, u1), bfpair(u2, u3));
        // conv2 logits: channels 4cp4..4cp4+3 and 64+4cp4..64+4cp4+3
        const float4* w2 = (const float4*)w2v;
        float4 wa = w2[2 * cp4], wb = w2[2 * cp4 + 1];
        float4 wc = w2[32 + 2 * cp4], wd = w2[32 + 2 * cp4 + 1];
        float p0 = v0*wa.x + v1*wa.z + v2*wb.x + v3*wb.z + u0*wc.x + u1*wc.z + u2*wd.x + u3*wd.z;
        float p1 = v0*wa.y + v1*wa.w + v2*wb.y + v3*wb.w + u0*wc.y + u1*wc.w + u2*wd.y + u3*wd.w;
        p0 += __shfl_xor(p0, 1); p0 += __shfl_xor(p0, 2);
        p0 += __shfl_xor(p0, 4); p0 += __shfl_xor(p0, 8);
        p1 += __shfl_xor(p1, 1); p1 += __shfl_xor(p1, 2);
        p1 += __shfl_xor(p1, 4); p1 += __shfl_xor(p1, 8);
        if (cp4 == 0) { als2[n] = p0; ald2[n] = p1; }
    }
}

// ---------------- GEMM2 (MFMA): h2b = bf16( o1b @ (W2hi+W2lo) ), dword w = chs (w, w+16) ----------------
__global__ __launch_bounds__(256) void k_gemm2(const uint4* __restrict__ ob4,
                                               const float* __restrict__ W,
                                               uint* __restrict__ h2b) {
    __shared__ uint4 WH[512];           // Wt_hi[n 0..31][k] swizzled, 8 KB
    __shared__ uint4 WL[512];
    int t = threadIdx.x;
    uint* whw = (uint*)WH;
    uint* wlw = (uint*)WL;
    for (int it = 0; it < 4; ++it) {
        int u = it * 256 + t;
        int n = u & 31, kq = u >> 5;
        float w0 = W[(kq * 4 + 0) * 32 + n];
        float w1 = W[(kq * 4 + 1) * 32 + n];
        float w2 = W[(kq * 4 + 2) * 32 + n];
        float w3 = W[(kq * 4 + 3) * 32 + n];
        uint h0 = bfr(w0), h1 = bfr(w1), h2 = bfr(w2), h3 = bfr(w3);
        float l0 = w0 - __uint_as_float(h0 << 16);
        float l1 = w1 - __uint_as_float(h1 << 16);
        float l2 = w2 - __uint_as_float(h2 << 16);
        float l3 = w3 - __uint_as_float(h3 << 16);
        int word = n * 64 + (((kq >> 1) ^ (n & 7)) << 2) + (kq & 1) * 2;
        *(uint2*)&whw[word] = make_uint2(h0 | (h1 << 16), h2 | (h3 << 16));
        *(uint2*)&wlw[word] = make_uint2(bfr(l0) | (bfr(l1) << 16), bfr(l2) | (bfr(l3) << 16));
    }
    __syncthreads();
    int l = t & 63, wid = t >> 6;
    int lr = l & 15, lg = l >> 4;
    int rowb = blockIdx.x * 128 + wid * 32;
    f32x4 acc[2][2] = {};
#pragma unroll
    for (int ks = 0; ks < 4; ++ks) {
        uint4 av0 = ob4[(rowb + lr) * 16 + ks * 4 + lg];
        uint4 av1 = ob4[(rowb + 16 + lr) * 16 + ks * 4 + lg];
        bf16x8 a0 = *reinterpret_cast<bf16x8*>(&av0);
        bf16x8 a1 = *reinterpret_cast<bf16x8*>(&av1);
        int quw = ks * 4 + lg;
#pragma unroll
        for (int nt = 0; nt < 2; ++nt) {
            int n = nt * 16 + lr;
            int idx = n * 16 + (quw ^ (n & 7));
            bf16x8 bh = *reinterpret_cast<bf16x8*>(&WH[idx]);
            bf16x8 bl = *reinterpret_cast<bf16x8*>(&WL[idx]);
            acc[0][nt] = __builtin_amdgcn_mfma_f32_16x16x32_bf16(a0, bh, acc[0][nt], 0, 0, 0);
            acc[0][nt] = __builtin_amdgcn_mfma_f32_16x16x32_bf16(a0, bl, acc[0][nt], 0, 0, 0);
            acc[1][nt] = __builtin_amdgcn_mfma_f32_16x16x32_bf16(a1, bh, acc[1][nt], 0, 0, 0);
            acc[1][nt] = __builtin_amdgcn_mfma_f32_16x16x32_bf16(a1, bl, acc[1][nt], 0, 0, 0);
        }
    }
#pragma unroll
    for (int mt = 0; mt < 2; ++mt)
#pragma unroll
        for (int r = 0; r < 4; ++r) {
            int row = rowb + mt * 16 + 4 * lg + r;
            if (row < N_NODES)
                h2b[row * 16 + lr] = bfpair(acc[mt][0][r], acc[mt][1][r]);
        }
}

// ---------------- agg2: single pass, eighth-wave per edge, slot-based ----------------
__global__ __launch_bounds__(256) void k_agg2(const uint2* __restrict__ h2b2,
                                              const int* __restrict__ pos, const int* __restrict__ esrc,
                                              const float* __restrict__ als, const float* __restrict__ ald,
                                              const float* __restrict__ b2,
                                              float* __restrict__ o2) {
    int l = threadIdx.x & 63;
    int wv = threadIdx.x >> 6;
    int n = blockIdx.x * 4 + wv;
    int s = n << 6;
    int e = s + min(pos[n], SLOT);
    int sub = l >> 3, cp8 = l & 7;       // dwords 2cp8, 2cp8+1 -> chs {2cp8(+1), 2cp8(+1)+16}
    float ad = ald[n];
    float a0 = 0, a1 = 0, a2 = 0, a3 = 0, ss = 0;
#pragma unroll 4
    for (int i = s + sub; i < e; i += 8) {
        int sa = esrc[i];
        float z = als[sa] + ad;
        float wgt = exp2fast(fmaxf(z, NEG_SLOPE * z));
        uint2 d = h2b2[sa * 8 + cp8];
        ss += wgt;
        a0 += wgt * bflo(d.x); a1 += wgt * bfhi(d.x);
        a2 += wgt * bflo(d.y); a3 += wgt * bfhi(d.y);
    }
    ss += __shfl_xor(ss, 8); ss += __shfl_xor(ss, 16); ss += __shfl_xor(ss, 32);
    a0 += __shfl_xor(a0, 8); a0 += __shfl_xor(a0, 16); a0 += __shfl_xor(a0, 32);
    a1 += __shfl_xor(a1, 8); a1 += __shfl_xor(a1, 16); a1 += __shfl_xor(a1, 32);
    a2 += __shfl_xor(a2, 8); a2 += __shfl_xor(a2, 16); a2 += __shfl_xor(a2, 32);
    a3 += __shfl_xor(a3, 8); a3 += __shfl_xor(a3, 16); a3 += __shfl_xor(a3, 32);
    if (sub == 0) {
        float inv = 1.f / ss;
        int c = 2 * cp8;
        float2 lo = { eluf(a0 * inv + b2[c]),      eluf(a2 * inv + b2[c + 1]) };
        float2 hi = { eluf(a1 * inv + b2[c + 16]), eluf(a3 * inv + b2[c + 17]) };
        *(float2*)&o2[n * 32 + c]      = lo;
        *(float2*)&o2[n * 32 + 16 + c] = hi;
    }
}

// ---------------- fused pool + final linear (inline boundary search) ----------------
__global__ __launch_bounds__(256) void k_poolfinal(const float* __restrict__ out2,
                                                   const int* __restrict__ batch,
                                                   const float* __restrict__ Wl,
                                                   const float* __restrict__ bl,
                                                   float* __restrict__ out) {
    __shared__ float red[4][32];
    __shared__ float pooled[32];
    int g = blockIdx.x;
    int s = 0, hi = N_NODES;
    while (s < hi) { int mid = (s + hi) >> 1; if (batch[mid] < g) s = mid + 1; else hi = mid; }
    int e = s; hi = N_NODES;
    while (e < hi) { int mid = (e + hi) >> 1; if (batch[mid] < g + 1) e = mid + 1; else hi = mid; }
    int t = threadIdx.x;
    int c = t & 31, r = t >> 5;
    float acc = 0.f;
    for (int i = s + r; i < e; i += 8)
        acc += out2[i * 32 + c];
    acc += __shfl_xor(acc, 32);
    if ((t & 63) < 32) red[t >> 6][c] = acc;
    __syncthreads();
    if (t < 32) {
        float v = red[0][t] + red[1][t] + red[2][t] + red[3][t];
        float cnt = fmaxf((float)(e - s), 1.f);
        pooled[t] = v / cnt;
    }
    __syncthreads();
    if (t < OUTC) {
        float a = 0.f;
        for (int cc = 0; cc < HIDC; cc++)
            a += pooled[cc] * Wl[cc * OUTC + t];
        out[g * OUTC + t] = a + bl[t];
    }
}

extern "C" void kernel_launch(void* const* d_in, const int* in_sizes, int n_in,
                              void* d_out, int out_size, void* d_ws, size_t ws_size,
                              hipStream_t stream) {
    (void)in_sizes; (void)n_in; (void)out_size; (void)ws_size;
    const float* x    = (const float*)d_in[0];
    const int*   ei   = (const int*)d_in[1];
    const int*   srcA = ei;
    const int*   dstA = ei + N_EDGES;
    const int*   batch = (const int*)d_in[2];
    const float* W1  = (const float*)d_in[3];
    const float* a1s = (const float*)d_in[4];
    const float* a1d = (const float*)d_in[5];
    const float* b1  = (const float*)d_in[6];
    const float* W2  = (const float*)d_in[7];
    const float* a2s = (const float*)d_in[8];
    const float* a2d = (const float*)d_in[9];
    const float* b2  = (const float*)d_in[10];
    const float* Wl  = (const float*)d_in[11];
    const float* bl  = (const float*)d_in[12];
    float* out = (float*)d_out;

    char* w = (char*)d_ws;
    auto alloc = [&](size_t bytes) -> void* {
        void* p = (void*)w;
        w += (bytes + 255) & ~(size_t)255;
        return p;
    };
    uint*  h1b  = (uint*)alloc((size_t)N_NODES * 64 * 4);    // 12.8 MB
    uint*  o1b  = (uint*)alloc((size_t)NPAD * 64 * 4);       // 12.85 MB
    uint*  h2b  = (uint*)alloc((size_t)N_NODES * 16 * 4);    // 3.2 MB
    float* o2   = (float*)alloc((size_t)N_NODES * 32 * 4);   // 6.4 MB
    float* als1 = (float*)alloc((size_t)N_NODES * 4 * 4);
    float* ald1 = (float*)alloc((size_t)N_NODES * 4 * 4);
    float* als2 = (float*)alloc((size_t)N_NODES * 4);
    float* ald2 = (float*)alloc((size_t)N_NODES * 4);
    float* w2v  = (float*)alloc(256 * 4);
    int*   pos  = (int*)alloc((size_t)N_NODES * 4);
    int*   esrc = (int*)alloc((size_t)N_NODES * SLOT * 4);   // 12.8 MB slots

    hipMemsetAsync(pos, 0, (size_t)N_NODES * 4, stream);
    k_g1scat<<<GEMM_BLKS + SCAT_BLKS + 1, 256, 0, stream>>>(x, W1, a1s, a1d,
                                                            h1b, (float4*)als1, (float4*)ald1,
                                                            srcA, dstA, pos, esrc,
                                                            W2, a2s, a2d, w2v);
    k_agg1<<<N_NODES / 4, 256, 0, stream>>>((const uint4*)h1b, pos, esrc,
                                            (const float2*)als1, (const float2*)ald1, b1, w2v,
                                            (uint2*)o1b, als2, ald2);
    k_gemm2<<<NPAD / 128, 256, 0, stream>>>((const uint4*)o1b, W2, h2b);
    k_agg2<<<N_NODES / 4, 256, 0, stream>>>((const uint2*)h2b, pos, esrc, als2, ald2, b2, o2);
    k_poolfinal<<<NGRAPH, 256, 0, stream>>>(o2, batch, Wl, bl, out);
}